// Round 1
// baseline (2360.255 us; speedup 1.0000x reference)
//
#include <hip/hip_runtime.h>
#include <hip/hip_bf16.h>
#include <math.h>

#define N_NODES 10000
#define N_EDGES 160000
#define FEAT 739
#define CCH 256
#define HEADS 8
#define LAYERS 4
#define NGR 16
#define HC 2048          // HEADS * CCH
#define E_TOT (N_EDGES + N_NODES)

// ---------------------------------------------------------------- GEMM (fp32)
// C[M,N] = A[M,K] @ B[K,N] (+ bias[N]); BM=128, BN=64, BK=16, 256 thr, 8x4/thr
#define BM 128
#define BN 64
#define BK 16

__global__ __launch_bounds__(256) void gemm_f32(
    const float* __restrict__ A, const float* __restrict__ B,
    float* __restrict__ C, const float* __restrict__ bias,
    int M, int N, int K)
{
  __shared__ float As[BK][BM + 4];   // stride 132 floats -> 16B-aligned rows
  __shared__ float Bs[BK][BN + 4];   // stride 68 floats  -> 16B-aligned rows
  const int tid  = threadIdx.x;
  const int row0 = blockIdx.y * BM;
  const int col0 = blockIdx.x * BN;
  const int tx   = tid & 15;
  const int ty   = tid >> 4;
  const int la_k = tid & 15;         // A: k within tile
  const int la_m = tid >> 4;         // A: row base (step 16)
  const int lb_k = tid >> 4;         // B: k within tile
  const int lb_n = (tid & 15) * 4;   // B: col (float4)

  float acc[8][4];
  #pragma unroll
  for (int i = 0; i < 8; i++)
    #pragma unroll
    for (int j = 0; j < 4; j++) acc[i][j] = 0.f;

  for (int k0 = 0; k0 < K; k0 += BK) {
    #pragma unroll
    for (int i = 0; i < 8; i++) {
      int m  = la_m + i * 16;
      int r  = row0 + m;
      int kk = k0 + la_k;
      float v = 0.f;
      if (r < M && kk < K) v = A[(size_t)r * K + kk];
      As[la_k][m] = v;
    }
    {
      int kk = k0 + lb_k;
      float4 v = make_float4(0.f, 0.f, 0.f, 0.f);
      if (kk < K) v = *(const float4*)(&B[(size_t)kk * N + col0 + lb_n]);
      *(float4*)(&Bs[lb_k][lb_n]) = v;
    }
    __syncthreads();
    #pragma unroll
    for (int k = 0; k < BK; k++) {
      float a[8], b[4];
      *(float4*)&a[0] = *(const float4*)&As[k][ty * 8];
      *(float4*)&a[4] = *(const float4*)&As[k][ty * 8 + 4];
      *(float4*)&b[0] = *(const float4*)&Bs[k][tx * 4];
      #pragma unroll
      for (int i = 0; i < 8; i++)
        #pragma unroll
        for (int j = 0; j < 4; j++)
          acc[i][j] = fmaf(a[i], b[j], acc[i][j]);
    }
    __syncthreads();
  }
  #pragma unroll
  for (int i = 0; i < 8; i++) {
    int r = row0 + ty * 8 + i;
    if (r >= M) continue;
    #pragma unroll
    for (int j = 0; j < 4; j++) {
      int c = col0 + tx * 4 + j;
      float v = acc[i][j];
      if (bias) v += bias[c];
      C[(size_t)r * N + c] = v;
    }
  }
}

// ---------------------------------------------------------------- CSR build
__global__ void degree_kernel(const int* __restrict__ ei, int* __restrict__ cnt)
{
  int e = blockIdx.x * 256 + threadIdx.x;
  if (e >= E_TOT) return;
  int d = (e < N_EDGES) ? ei[N_EDGES + e] : (e - N_EDGES);
  atomicAdd(&cnt[d], 1);
}

__global__ void scan_kernel(const int* __restrict__ cnt, int* __restrict__ off, int n)
{
  __shared__ int part[1024];
  const int t = threadIdx.x;
  const int chunk = (n + 1023) / 1024;
  int s = 0;
  for (int i = 0; i < chunk; i++) {
    int idx = t * chunk + i;
    if (idx < n) s += cnt[idx];
  }
  part[t] = s;
  __syncthreads();
  for (int d = 1; d < 1024; d <<= 1) {
    int v = (t >= d) ? part[t - d] : 0;
    __syncthreads();
    part[t] += v;
    __syncthreads();
  }
  int run = (t == 0) ? 0 : part[t - 1];
  for (int i = 0; i < chunk; i++) {
    int idx = t * chunk + i;
    if (idx < n) { off[idx] = run; run += cnt[idx]; }
  }
  if (t == 1023) off[n] = part[1023];
}

__global__ void copy_kernel(const int* __restrict__ src, int* __restrict__ dst, int n)
{
  int i = blockIdx.x * 256 + threadIdx.x;
  if (i < n) dst[i] = src[i];
}

__global__ void fill_kernel(const int* __restrict__ ei, int* __restrict__ cursor,
                            int* __restrict__ csr)
{
  int e = blockIdx.x * 256 + threadIdx.x;
  if (e >= E_TOT) return;
  int s, d;
  if (e < N_EDGES) { s = ei[e]; d = ei[N_EDGES + e]; }
  else             { s = e - N_EDGES; d = s; }
  int pos = atomicAdd(&cursor[d], 1);
  csr[pos] = s;
}

// ---------------------------------------------------------------- fused GATv2 edge pass
// 1 block = 1 dst node. 256 thr = 8 heads x 32 lanes, 8 channels each.
// Online softmax over incoming edges; single gather of xl[src] per edge.
__global__ __launch_bounds__(256) void gat_edge(
    const float* __restrict__ xl, const float* __restrict__ xr,
    const int* __restrict__ off, const int* __restrict__ csr,
    const float* __restrict__ att, const float* __restrict__ bias,
    float* __restrict__ hout)
{
  __shared__ float red[256 * 8];
  const int n = blockIdx.x;
  const int t = threadIdx.x;
  const int lane32 = t & 31;
  const size_t fo = (size_t)(t >> 5) * CCH + lane32 * 8;  // offset in 2048-row

  float xr8[8], att8[8];
  *(float4*)&xr8[0]  = *(const float4*)&xr[(size_t)n * HC + fo];
  *(float4*)&xr8[4]  = *(const float4*)&xr[(size_t)n * HC + fo + 4];
  *(float4*)&att8[0] = *(const float4*)&att[fo];
  *(float4*)&att8[4] = *(const float4*)&att[fo + 4];

  float m_run = -INFINITY, d_run = 0.f;
  float acc[8];
  #pragma unroll
  for (int j = 0; j < 8; j++) acc[j] = 0.f;

  const int e0 = off[n], e1 = off[n + 1];
  for (int i = e0; i < e1; i++) {
    const int s = csr[i];
    float xl8[8];
    const float* xlp = &xl[(size_t)s * HC + fo];
    *(float4*)&xl8[0] = *(const float4*)&xlp[0];
    *(float4*)&xl8[4] = *(const float4*)&xlp[4];
    float p = 0.f;
    #pragma unroll
    for (int j = 0; j < 8; j++) {
      float v = xl8[j] + xr8[j];
      v = (v >= 0.f) ? v : 0.2f * v;      // leaky_relu(0.2)
      p = fmaf(att8[j], v, p);
    }
    #pragma unroll
    for (int d = 1; d < 32; d <<= 1) p += __shfl_xor(p, d);  // head-group reduce
    float m_new = fmaxf(m_run, p);
    float sc = __expf(m_run - m_new);     // exp(-inf)=0 on first edge
    float pe = __expf(p - m_new);
    d_run = d_run * sc + pe;
    #pragma unroll
    for (int j = 0; j < 8; j++) acc[j] = fmaf(acc[j], sc, pe * xl8[j]);
    m_run = m_new;
  }

  const float w = 0.125f / (d_run + 1e-16f);  // /denom then head-mean
  #pragma unroll
  for (int j = 0; j < 8; j++) red[t * 8 + j] = acc[j] * w;
  __syncthreads();
  if (t < 32) {
    #pragma unroll
    for (int j = 0; j < 8; j++) {
      float s2 = 0.f;
      #pragma unroll
      for (int hh = 0; hh < 8; hh++) s2 += red[(hh * 32 + t) * 8 + j];
      hout[(size_t)n * CCH + t * 8 + j] = s2 + bias[t * 8 + j];
    }
  }
}

// ---------------------------------------------------------------- pool + head
__global__ void pool_kernel(const float* __restrict__ h, const int* __restrict__ batch,
                            float* __restrict__ pooled, int* __restrict__ gcnt)
{
  const int n = blockIdx.x, t = threadIdx.x;
  const int g = batch[n];
  atomicAdd(&pooled[g * CCH + t], h[(size_t)n * CCH + t]);
  if (t == 0) atomicAdd(&gcnt[g], 1);
}

__global__ void head_kernel(const float* __restrict__ pooled, const int* __restrict__ gcnt,
                            const float* __restrict__ hw, const float* __restrict__ hb,
                            float* __restrict__ out)
{
  __shared__ float r[256];
  const int g = blockIdx.x, t = threadIdx.x;
  float c = (float)gcnt[g];
  if (c < 1.f) c = 1.f;
  r[t] = pooled[g * CCH + t] / c * hw[t];
  __syncthreads();
  for (int s2 = 128; s2 > 0; s2 >>= 1) {
    if (t < s2) r[t] += r[t + s2];
    __syncthreads();
  }
  if (t == 0) out[g] = r[0] + hb[0];
}

// ---------------------------------------------------------------- launcher
extern "C" void kernel_launch(void* const* d_in, const int* in_sizes, int n_in,
                              void* d_out, int out_size, void* d_ws, size_t ws_size,
                              hipStream_t stream)
{
  const float* x        = (const float*)d_in[0];
  const int*   ei       = (const int*)d_in[1];
  const int*   batch    = (const int*)d_in[2];
  const float* dense_w  = (const float*)d_in[3];
  const float* dense_b  = (const float*)d_in[4];
  const float* conv_wl  = (const float*)d_in[5];
  const float* conv_wr  = (const float*)d_in[6];
  const float* conv_att = (const float*)d_in[7];
  const float* conv_b   = (const float*)d_in[8];
  const float* head_w   = (const float*)d_in[9];
  const float* head_b   = (const float*)d_in[10];
  float* out = (float*)d_out;

  char* ws = (char*)d_ws;
  size_t off_b = 0;
  auto alloc = [&](size_t bytes) -> char* {
    char* r = ws + off_b;
    off_b += (bytes + 255) & ~(size_t)255;
    return r;
  };
  float* h      = (float*)alloc((size_t)N_NODES * CCH * 4);   // 10.24 MB (layer io, in-place)
  float* xl     = (float*)alloc((size_t)N_NODES * HC * 4);    // 81.92 MB
  float* xr     = (float*)alloc((size_t)N_NODES * HC * 4);    // 81.92 MB
  int*   offs   = (int*)alloc((N_NODES + 1) * 4);
  int*   cnt    = (int*)alloc(N_NODES * 4);                   // degree, then cursor
  int*   csr    = (int*)alloc(E_TOT * 4);
  float* pooled = (float*)alloc(NGR * CCH * 4);
  int*   gcnt   = (int*)alloc(NGR * 4);

  // ---- CSR by dst (graph fixed across layers)
  hipMemsetAsync(cnt, 0, N_NODES * 4, stream);
  degree_kernel<<<(E_TOT + 255) / 256, 256, 0, stream>>>(ei, cnt);
  scan_kernel<<<1, 1024, 0, stream>>>(cnt, offs, N_NODES);
  copy_kernel<<<(N_NODES + 255) / 256, 256, 0, stream>>>(offs, cnt, N_NODES);
  fill_kernel<<<(E_TOT + 255) / 256, 256, 0, stream>>>(ei, cnt, csr);

  // ---- dense: h = x @ dense_w + dense_b
  {
    dim3 g((CCH + BN - 1) / BN, (N_NODES + BM - 1) / BM);
    gemm_f32<<<g, 256, 0, stream>>>(x, dense_w, h, dense_b, N_NODES, CCH, FEAT);
  }

  // ---- 4 GATv2 layers
  for (int l = 0; l < LAYERS; l++) {
    dim3 g((HC + BN - 1) / BN, (N_NODES + BM - 1) / BM);
    gemm_f32<<<g, 256, 0, stream>>>(h, conv_wl + (size_t)l * CCH * HC, xl, nullptr,
                                    N_NODES, HC, CCH);
    gemm_f32<<<g, 256, 0, stream>>>(h, conv_wr + (size_t)l * CCH * HC, xr, nullptr,
                                    N_NODES, HC, CCH);
    gat_edge<<<N_NODES, 256, 0, stream>>>(xl, xr, offs, csr,
                                          conv_att + (size_t)l * HC,
                                          conv_b + (size_t)l * CCH, h);
  }

  // ---- global mean pool + head
  hipMemsetAsync(pooled, 0, NGR * CCH * 4, stream);
  hipMemsetAsync(gcnt, 0, NGR * 4, stream);
  pool_kernel<<<N_NODES, 256, 0, stream>>>(h, batch, pooled, gcnt);
  head_kernel<<<NGR, 256, 0, stream>>>(pooled, gcnt, head_w, head_b, out);
}

// Round 2
// 931.238 us; speedup vs baseline: 2.5345x; 2.5345x over previous
//
#include <hip/hip_runtime.h>
#include <hip/hip_bf16.h>
#include <math.h>

#define N_NODES 10000
#define M_PAD   10112          // 79 * 128
#define N_EDGES 160000
#define FEAT 739
#define KD_PAD 768             // FEAT padded to 32
#define CCH 256
#define HEADS 8
#define LAYERS 4
#define NGR 16
#define HC 2048                // HEADS * CCH
#define E_TOT (N_EDGES + N_NODES)

typedef _Float16 half8_t __attribute__((ext_vector_type(8)));
typedef float    f32x4   __attribute__((ext_vector_type(4)));

__device__ __forceinline__ void gload16(const void* g, void* l) {
  __builtin_amdgcn_global_load_lds(
      (const __attribute__((address_space(1))) void*)g,
      (__attribute__((address_space(3))) void*)l, 16, 0, 0);
}

// ---------------------------------------------------------------- MFMA GEMM (fp16 in, fp32 acc)
// C[M,N] = A[M,K] @ BT[N,K]^T (+bias). 256 thr = 4 waves (2x2), wave tile 64x64,
// 16 frags of 16x16 via mfma_f32_16x16x32_f16. BK=32, double-buffered LDS,
// global_load_lds width-16 staging. A must have M_PAD rows (pad garbage finite).
__global__ __launch_bounds__(256) void gemm_h16(
    const _Float16* __restrict__ A,   // [M_PAD][K]
    const _Float16* __restrict__ BT,  // [N][K]
    float* __restrict__ C,            // [M][N] or null
    _Float16* __restrict__ C16,       // [M][N] or null
    const float* __restrict__ bias,   // [N] or null
    int M, int N, int K)
{
  __shared__ __align__(16) _Float16 As[2][128][32];
  __shared__ __align__(16) _Float16 Bs[2][128][32];
  const int tid  = threadIdx.x;
  const int wave = tid >> 6, lane = tid & 63;
  const int wm = wave >> 1, wn = wave & 1;
  const int m0 = blockIdx.y * 128, n0 = blockIdx.x * 128;
  const int l15 = lane & 15, l4 = lane >> 4;

  f32x4 acc[4][4];
  #pragma unroll
  for (int i = 0; i < 4; i++)
    #pragma unroll
    for (int j = 0; j < 4; j++) acc[i][j] = (f32x4){0.f, 0.f, 0.f, 0.f};

  auto stage = [&](int buf, int k0) {
    #pragma unroll
    for (int i = 0; i < 2; i++) {
      int q = i * 256 + tid;
      int row = q >> 2, ch = (q & 3) * 8;
      gload16(&A[(size_t)(m0 + row) * K + k0 + ch], &As[buf][row][ch]);
    }
    #pragma unroll
    for (int i = 0; i < 2; i++) {
      int q = i * 256 + tid;
      int row = q >> 2, ch = (q & 3) * 8;
      gload16(&BT[(size_t)(n0 + row) * K + k0 + ch], &Bs[buf][row][ch]);
    }
  };

  const int NT = K >> 5;
  stage(0, 0);
  for (int t = 0; t < NT; t++) {
    __syncthreads();                       // drains vmcnt(0): buf t&1 ready + reuse-safe
    if (t + 1 < NT) stage((t + 1) & 1, (t + 1) << 5);
    const int b = t & 1;
    half8_t af[4], bf[4];
    #pragma unroll
    for (int f = 0; f < 4; f++)
      af[f] = *(const half8_t*)&As[b][wm * 64 + f * 16 + l15][l4 * 8];
    #pragma unroll
    for (int f = 0; f < 4; f++)
      bf[f] = *(const half8_t*)&Bs[b][wn * 64 + f * 16 + l15][l4 * 8];
    #pragma unroll
    for (int i = 0; i < 4; i++)
      #pragma unroll
      for (int j = 0; j < 4; j++)
        acc[i][j] = __builtin_amdgcn_mfma_f32_16x16x32_f16(af[i], bf[j], acc[i][j], 0, 0, 0);
  }

  // epilogue: C/D layout col=lane&15, row=(lane>>4)*4+reg  [m89-verified]
  #pragma unroll
  for (int j = 0; j < 4; j++) {
    const int col = n0 + wn * 64 + j * 16 + l15;
    const float bv = bias ? bias[col] : 0.f;
    #pragma unroll
    for (int i = 0; i < 4; i++) {
      #pragma unroll
      for (int r = 0; r < 4; r++) {
        const int row = m0 + wm * 64 + i * 16 + l4 * 4 + r;
        if (row < M) {
          const float v = acc[i][j][r] + bv;
          if (C)   C[(size_t)row * N + col]   = v;
          if (C16) C16[(size_t)row * N + col] = (_Float16)v;
        }
      }
    }
  }
}

// ---------------------------------------------------------------- converts / transposes
// out[N][Kpad] = (fp16) in[K][N]^T, zero-pad k>=K
__global__ __launch_bounds__(256) void transpose_w(
    const float* __restrict__ in, _Float16* __restrict__ out, int K, int N, int Kpad)
{
  __shared__ float tile[32][33];
  const int kb = blockIdx.y * 32, nb = blockIdx.x * 32;
  const int tx = threadIdx.x & 31, ty = threadIdx.x >> 5;
  #pragma unroll
  for (int i = 0; i < 32; i += 8) {
    int k = kb + ty + i;
    tile[ty + i][tx] = (k < K) ? in[(size_t)k * N + nb + tx] : 0.f;
  }
  __syncthreads();
  #pragma unroll
  for (int i = 0; i < 32; i += 8) {
    int n = nb + ty + i;
    out[(size_t)n * Kpad + kb + tx] = (_Float16)tile[tx][ty + i];
  }
}

// x16[M_PAD][KD_PAD] = fp16(x[10000][739]), zero-padded
__global__ void conv_x(const float* __restrict__ x, _Float16* __restrict__ x16)
{
  const int r = blockIdx.y;
  const int c = blockIdx.x * 256 + threadIdx.x;
  float v = (r < N_NODES && c < FEAT) ? x[(size_t)r * FEAT + c] : 0.f;
  x16[(size_t)r * KD_PAD + c] = (_Float16)v;
}

// ---------------------------------------------------------------- CSR build
__global__ void degree_kernel(const int* __restrict__ ei, int* __restrict__ cnt)
{
  int e = blockIdx.x * 256 + threadIdx.x;
  if (e >= E_TOT) return;
  int d = (e < N_EDGES) ? ei[N_EDGES + e] : (e - N_EDGES);
  atomicAdd(&cnt[d], 1);
}

__global__ void scan_kernel(const int* __restrict__ cnt, int* __restrict__ off, int n)
{
  __shared__ int part[1024];
  const int t = threadIdx.x;
  const int chunk = (n + 1023) / 1024;
  int s = 0;
  for (int i = 0; i < chunk; i++) {
    int idx = t * chunk + i;
    if (idx < n) s += cnt[idx];
  }
  part[t] = s;
  __syncthreads();
  for (int d = 1; d < 1024; d <<= 1) {
    int v = (t >= d) ? part[t - d] : 0;
    __syncthreads();
    part[t] += v;
    __syncthreads();
  }
  int run = (t == 0) ? 0 : part[t - 1];
  for (int i = 0; i < chunk; i++) {
    int idx = t * chunk + i;
    if (idx < n) { off[idx] = run; run += cnt[idx]; }
  }
  if (t == 1023) off[n] = part[1023];
}

__global__ void copy_kernel(const int* __restrict__ src, int* __restrict__ dst, int n)
{
  int i = blockIdx.x * 256 + threadIdx.x;
  if (i < n) dst[i] = src[i];
}

__global__ void fill_kernel(const int* __restrict__ ei, int* __restrict__ cursor,
                            int* __restrict__ csr)
{
  int e = blockIdx.x * 256 + threadIdx.x;
  if (e >= E_TOT) return;
  int s, d;
  if (e < N_EDGES) { s = ei[e]; d = ei[N_EDGES + e]; }
  else             { s = e - N_EDGES; d = s; }
  int pos = atomicAdd(&cursor[d], 1);
  csr[pos] = s;
}

// ---------------------------------------------------------------- fused GATv2 edge pass
// 1 block = 1 dst node. 256 thr = 8 heads x 32 lanes, 8 channels each.
// Online softmax; fp16 gathers (16B/lane), fp32 math. Writes h fp32 + fp16.
__global__ __launch_bounds__(256) void gat_edge(
    const _Float16* __restrict__ xl, const _Float16* __restrict__ xr,
    const int* __restrict__ off, const int* __restrict__ csr,
    const float* __restrict__ att, const float* __restrict__ bias,
    float* __restrict__ hout, _Float16* __restrict__ hout16)
{
  __shared__ float red[256 * 8];
  const int n = blockIdx.x;
  const int t = threadIdx.x;
  const int lane32 = t & 31;
  const size_t fo = (size_t)(t >> 5) * CCH + lane32 * 8;

  float xr8[8], att8[8];
  {
    half8_t v = *(const half8_t*)&xr[(size_t)n * HC + fo];
    #pragma unroll
    for (int j = 0; j < 8; j++) xr8[j] = (float)v[j];
    *(float4*)&att8[0] = *(const float4*)&att[fo];
    *(float4*)&att8[4] = *(const float4*)&att[fo + 4];
  }

  float m_run = -INFINITY, d_run = 0.f;
  float acc[8];
  #pragma unroll
  for (int j = 0; j < 8; j++) acc[j] = 0.f;

  const int e0 = off[n], e1 = off[n + 1];
  for (int i = e0; i < e1; i++) {
    const int s = csr[i];
    half8_t v = *(const half8_t*)&xl[(size_t)s * HC + fo];
    float xl8[8];
    float p = 0.f;
    #pragma unroll
    for (int j = 0; j < 8; j++) {
      xl8[j] = (float)v[j];
      float m = xl8[j] + xr8[j];
      m = (m >= 0.f) ? m : 0.2f * m;      // leaky_relu(0.2)
      p = fmaf(att8[j], m, p);
    }
    #pragma unroll
    for (int d = 1; d < 32; d <<= 1) p += __shfl_xor(p, d);
    float m_new = fmaxf(m_run, p);
    float sc = __expf(m_run - m_new);
    float pe = __expf(p - m_new);
    d_run = d_run * sc + pe;
    #pragma unroll
    for (int j = 0; j < 8; j++) acc[j] = fmaf(acc[j], sc, pe * xl8[j]);
    m_run = m_new;
  }

  const float w = 0.125f / (d_run + 1e-16f);
  #pragma unroll
  for (int j = 0; j < 8; j++) red[t * 8 + j] = acc[j] * w;
  __syncthreads();
  if (t < 32) {
    #pragma unroll
    for (int j = 0; j < 8; j++) {
      float s2 = 0.f;
      #pragma unroll
      for (int hh = 0; hh < 8; hh++) s2 += red[(hh * 32 + t) * 8 + j];
      s2 += bias[t * 8 + j];
      hout[(size_t)n * CCH + t * 8 + j] = s2;
      hout16[(size_t)n * CCH + t * 8 + j] = (_Float16)s2;
    }
  }
}

// ---------------------------------------------------------------- pool + head
__global__ void pool_kernel(const float* __restrict__ h, const int* __restrict__ batch,
                            float* __restrict__ pooled, int* __restrict__ gcnt)
{
  const int n = blockIdx.x, t = threadIdx.x;
  const int g = batch[n];
  atomicAdd(&pooled[g * CCH + t], h[(size_t)n * CCH + t]);
  if (t == 0) atomicAdd(&gcnt[g], 1);
}

__global__ void head_kernel(const float* __restrict__ pooled, const int* __restrict__ gcnt,
                            const float* __restrict__ hw, const float* __restrict__ hb,
                            float* __restrict__ out)
{
  __shared__ float r[256];
  const int g = blockIdx.x, t = threadIdx.x;
  float c = (float)gcnt[g];
  if (c < 1.f) c = 1.f;
  r[t] = pooled[g * CCH + t] / c * hw[t];
  __syncthreads();
  for (int s2 = 128; s2 > 0; s2 >>= 1) {
    if (t < s2) r[t] += r[t + s2];
    __syncthreads();
  }
  if (t == 0) out[g] = r[0] + hb[0];
}

// ---------------------------------------------------------------- launcher
extern "C" void kernel_launch(void* const* d_in, const int* in_sizes, int n_in,
                              void* d_out, int out_size, void* d_ws, size_t ws_size,
                              hipStream_t stream)
{
  const float* x        = (const float*)d_in[0];
  const int*   ei       = (const int*)d_in[1];
  const int*   batch    = (const int*)d_in[2];
  const float* dense_w  = (const float*)d_in[3];
  const float* dense_b  = (const float*)d_in[4];
  const float* conv_wl  = (const float*)d_in[5];
  const float* conv_wr  = (const float*)d_in[6];
  const float* conv_att = (const float*)d_in[7];
  const float* conv_b   = (const float*)d_in[8];
  const float* head_w   = (const float*)d_in[9];
  const float* head_b   = (const float*)d_in[10];
  float* out = (float*)d_out;

  char* ws = (char*)d_ws;
  size_t off_b = 0;
  auto alloc = [&](size_t bytes) -> char* {
    char* r = ws + off_b;
    off_b += (bytes + 255) & ~(size_t)255;
    return r;
  };
  float*     h      = (float*)alloc((size_t)N_NODES * CCH * 4);        // 10.2 MB
  _Float16*  h16    = (_Float16*)alloc((size_t)M_PAD * CCH * 2);       // 5.2 MB
  _Float16*  x16    = (_Float16*)alloc((size_t)M_PAD * KD_PAD * 2);    // 15.5 MB
  _Float16*  xl16   = (_Float16*)alloc((size_t)N_NODES * HC * 2);      // 41 MB
  _Float16*  xr16   = (_Float16*)alloc((size_t)N_NODES * HC * 2);      // 41 MB
  _Float16*  wdT    = (_Float16*)alloc((size_t)CCH * KD_PAD * 2);      // 0.4 MB
  _Float16*  wlT    = (_Float16*)alloc((size_t)LAYERS * HC * CCH * 2); // 4.2 MB
  _Float16*  wrT    = (_Float16*)alloc((size_t)LAYERS * HC * CCH * 2); // 4.2 MB
  int*   offs   = (int*)alloc((N_NODES + 1) * 4);
  int*   cnt    = (int*)alloc(N_NODES * 4);
  int*   csr    = (int*)alloc(E_TOT * 4);
  float* pooled = (float*)alloc(NGR * CCH * 4);
  int*   gcnt   = (int*)alloc(NGR * 4);

  // ---- CSR by dst
  hipMemsetAsync(cnt, 0, N_NODES * 4, stream);
  degree_kernel<<<(E_TOT + 255) / 256, 256, 0, stream>>>(ei, cnt);
  scan_kernel<<<1, 1024, 0, stream>>>(cnt, offs, N_NODES);
  copy_kernel<<<(N_NODES + 255) / 256, 256, 0, stream>>>(offs, cnt, N_NODES);
  fill_kernel<<<(E_TOT + 255) / 256, 256, 0, stream>>>(ei, cnt, csr);

  // ---- fp16 conversions / weight transposes
  {
    dim3 g(KD_PAD / 256, M_PAD);
    conv_x<<<g, 256, 0, stream>>>(x, x16);
  }
  transpose_w<<<dim3(CCH / 32, KD_PAD / 32), 256, 0, stream>>>(dense_w, wdT, FEAT, CCH, KD_PAD);
  for (int l = 0; l < LAYERS; l++) {
    transpose_w<<<dim3(HC / 32, CCH / 32), 256, 0, stream>>>(
        conv_wl + (size_t)l * CCH * HC, wlT + (size_t)l * HC * CCH, CCH, HC, CCH);
    transpose_w<<<dim3(HC / 32, CCH / 32), 256, 0, stream>>>(
        conv_wr + (size_t)l * CCH * HC, wrT + (size_t)l * HC * CCH, CCH, HC, CCH);
  }

  // ---- dense: h = x @ dense_w + dense_b  (fp32 + fp16 copies)
  gemm_h16<<<dim3(CCH / 128, M_PAD / 128), 256, 0, stream>>>(
      x16, wdT, h, h16, dense_b, N_NODES, CCH, KD_PAD);

  // ---- 4 GATv2 layers
  for (int l = 0; l < LAYERS; l++) {
    gemm_h16<<<dim3(HC / 128, M_PAD / 128), 256, 0, stream>>>(
        h16, wlT + (size_t)l * HC * CCH, nullptr, xl16, nullptr, N_NODES, HC, CCH);
    gemm_h16<<<dim3(HC / 128, M_PAD / 128), 256, 0, stream>>>(
        h16, wrT + (size_t)l * HC * CCH, nullptr, xr16, nullptr, N_NODES, HC, CCH);
    gat_edge<<<N_NODES, 256, 0, stream>>>(xl16, xr16, offs, csr,
                                          conv_att + (size_t)l * HC,
                                          conv_b + (size_t)l * CCH, h, h16);
  }

  // ---- global mean pool + head
  hipMemsetAsync(pooled, 0, NGR * CCH * 4, stream);
  hipMemsetAsync(gcnt, 0, NGR * 4, stream);
  pool_kernel<<<N_NODES, 256, 0, stream>>>(h, batch, pooled, gcnt);
  head_kernel<<<NGR, 256, 0, stream>>>(pooled, gcnt, head_w, head_b, out);
}

// Round 3
// 818.232 us; speedup vs baseline: 2.8846x; 1.1381x over previous
//
#include <hip/hip_runtime.h>
#include <hip/hip_bf16.h>
#include <math.h>

#define N_NODES 10000
#define M_PAD   10112          // 79 * 128
#define N_EDGES 160000
#define FEAT 739
#define KD_PAD 768             // FEAT padded to 32
#define CCH 256
#define HEADS 8
#define LAYERS 4
#define NGR 16
#define HC 2048                // HEADS * CCH
#define HC2 4096               // xl|xr concatenated row
#define E_TOT (N_EDGES + N_NODES)

typedef _Float16 half8_t __attribute__((ext_vector_type(8)));
typedef float    f32x4   __attribute__((ext_vector_type(4)));

__device__ __forceinline__ void gload16(const void* g, void* l) {
  __builtin_amdgcn_global_load_lds(
      (const __attribute__((address_space(1))) void*)g,
      (__attribute__((address_space(3))) void*)l, 16, 0, 0);
}

// ---------------------------------------------------------------- MFMA GEMM (fp16 in, fp32 acc)
// C[M,N] = A[M,K] @ BT[N,K]^T (+bias). 256 thr = 4 waves (2x2), wave tile 64x64,
// 16 frags of 16x16 via mfma_f32_16x16x32_f16. BK=32, double-buffered LDS,
// global_load_lds width-16 staging. A must have M_PAD rows (pad garbage finite).
__global__ __launch_bounds__(256) void gemm_h16(
    const _Float16* __restrict__ A,   // [M_PAD][K]
    const _Float16* __restrict__ BT,  // [N][K]
    float* __restrict__ C,            // [M][N] or null
    _Float16* __restrict__ C16,       // [M][N] or null
    const float* __restrict__ bias,   // [N] or null
    int M, int N, int K)
{
  __shared__ __align__(16) _Float16 As[2][128][32];
  __shared__ __align__(16) _Float16 Bs[2][128][32];
  const int tid  = threadIdx.x;
  const int wave = tid >> 6, lane = tid & 63;
  const int wm = wave >> 1, wn = wave & 1;
  const int m0 = blockIdx.y * 128, n0 = blockIdx.x * 128;
  const int l15 = lane & 15, l4 = lane >> 4;

  f32x4 acc[4][4];
  #pragma unroll
  for (int i = 0; i < 4; i++)
    #pragma unroll
    for (int j = 0; j < 4; j++) acc[i][j] = (f32x4){0.f, 0.f, 0.f, 0.f};

  auto stage = [&](int buf, int k0) {
    #pragma unroll
    for (int i = 0; i < 2; i++) {
      int q = i * 256 + tid;
      int row = q >> 2, ch = (q & 3) * 8;
      gload16(&A[(size_t)(m0 + row) * K + k0 + ch], &As[buf][row][ch]);
    }
    #pragma unroll
    for (int i = 0; i < 2; i++) {
      int q = i * 256 + tid;
      int row = q >> 2, ch = (q & 3) * 8;
      gload16(&BT[(size_t)(n0 + row) * K + k0 + ch], &Bs[buf][row][ch]);
    }
  };

  const int NT = K >> 5;
  stage(0, 0);
  for (int t = 0; t < NT; t++) {
    __syncthreads();                       // drains vmcnt(0): buf t&1 ready + reuse-safe
    if (t + 1 < NT) stage((t + 1) & 1, (t + 1) << 5);
    const int b = t & 1;
    half8_t af[4], bf[4];
    #pragma unroll
    for (int f = 0; f < 4; f++)
      af[f] = *(const half8_t*)&As[b][wm * 64 + f * 16 + l15][l4 * 8];
    #pragma unroll
    for (int f = 0; f < 4; f++)
      bf[f] = *(const half8_t*)&Bs[b][wn * 64 + f * 16 + l15][l4 * 8];
    #pragma unroll
    for (int i = 0; i < 4; i++)
      #pragma unroll
      for (int j = 0; j < 4; j++)
        acc[i][j] = __builtin_amdgcn_mfma_f32_16x16x32_f16(af[i], bf[j], acc[i][j], 0, 0, 0);
  }

  // epilogue: C/D layout col=lane&15, row=(lane>>4)*4+reg  [m89-verified]
  #pragma unroll
  for (int j = 0; j < 4; j++) {
    const int col = n0 + wn * 64 + j * 16 + l15;
    const float bv = bias ? bias[col] : 0.f;
    #pragma unroll
    for (int i = 0; i < 4; i++) {
      #pragma unroll
      for (int r = 0; r < 4; r++) {
        const int row = m0 + wm * 64 + i * 16 + l4 * 4 + r;
        if (row < M) {
          const float v = acc[i][j][r] + bv;
          if (C)   C[(size_t)row * N + col]   = v;
          if (C16) C16[(size_t)row * N + col] = (_Float16)v;
        }
      }
    }
  }
}

// ---------------------------------------------------------------- converts / transposes
// out[N][Kpad] = (fp16) in[K][N]^T, zero-pad k>=K
__global__ __launch_bounds__(256) void transpose_w(
    const float* __restrict__ in, _Float16* __restrict__ out, int K, int N, int Kpad)
{
  __shared__ float tile[32][33];
  const int kb = blockIdx.y * 32, nb = blockIdx.x * 32;
  const int tx = threadIdx.x & 31, ty = threadIdx.x >> 5;
  #pragma unroll
  for (int i = 0; i < 32; i += 8) {
    int k = kb + ty + i;
    tile[ty + i][tx] = (k < K) ? in[(size_t)k * N + nb + tx] : 0.f;
  }
  __syncthreads();
  #pragma unroll
  for (int i = 0; i < 32; i += 8) {
    int n = nb + ty + i;
    out[(size_t)n * Kpad + kb + tx] = (_Float16)tile[tx][ty + i];
  }
}

// x16[M_PAD][KD_PAD] = fp16(x[10000][739]), zero-padded
__global__ void conv_x(const float* __restrict__ x, _Float16* __restrict__ x16)
{
  const int r = blockIdx.y;
  const int c = blockIdx.x * 256 + threadIdx.x;
  float v = (r < N_NODES && c < FEAT) ? x[(size_t)r * FEAT + c] : 0.f;
  x16[(size_t)r * KD_PAD + c] = (_Float16)v;
}

// ---------------------------------------------------------------- CSR build
__global__ void degree_kernel(const int* __restrict__ ei, int* __restrict__ cnt)
{
  int e = blockIdx.x * 256 + threadIdx.x;
  if (e >= E_TOT) return;
  int d = (e < N_EDGES) ? ei[N_EDGES + e] : (e - N_EDGES);
  atomicAdd(&cnt[d], 1);
}

__global__ void scan_kernel(const int* __restrict__ cnt, int* __restrict__ off, int n)
{
  __shared__ int part[1024];
  const int t = threadIdx.x;
  const int chunk = (n + 1023) / 1024;
  int s = 0;
  for (int i = 0; i < chunk; i++) {
    int idx = t * chunk + i;
    if (idx < n) s += cnt[idx];
  }
  part[t] = s;
  __syncthreads();
  for (int d = 1; d < 1024; d <<= 1) {
    int v = (t >= d) ? part[t - d] : 0;
    __syncthreads();
    part[t] += v;
    __syncthreads();
  }
  int run = (t == 0) ? 0 : part[t - 1];
  for (int i = 0; i < chunk; i++) {
    int idx = t * chunk + i;
    if (idx < n) { off[idx] = run; run += cnt[idx]; }
  }
  if (t == 1023) off[n] = part[1023];
}

__global__ void copy_kernel(const int* __restrict__ src, int* __restrict__ dst, int n)
{
  int i = blockIdx.x * 256 + threadIdx.x;
  if (i < n) dst[i] = src[i];
}

__global__ void fill_kernel(const int* __restrict__ ei, int* __restrict__ cursor,
                            int* __restrict__ csr)
{
  int e = blockIdx.x * 256 + threadIdx.x;
  if (e >= E_TOT) return;
  int s, d;
  if (e < N_EDGES) { s = ei[e]; d = ei[N_EDGES + e]; }
  else             { s = e - N_EDGES; d = s; }
  int pos = atomicAdd(&cursor[d], 1);
  csr[pos] = s;
}

// goff[g] = first node index with batch >= g (batch sorted); goff[NGR] = N
__global__ void gbound_kernel(const int* __restrict__ batch, int* __restrict__ goff)
{
  int n = blockIdx.x * 256 + threadIdx.x;
  if (n >= N_NODES) return;
  if (n == 0) {
    for (int g = 0; g <= batch[0]; g++) goff[g] = 0;
  } else {
    int b0 = batch[n - 1], b1 = batch[n];
    for (int g = b0 + 1; g <= b1; g++) goff[g] = n;
  }
  if (n == N_NODES - 1) {
    for (int g = batch[n] + 1; g <= NGR; g++) goff[g] = N_NODES;
  }
}

// ---------------------------------------------------------------- fused GATv2 edge pass
// 1 block = 1 dst node. 256 thr = 8 heads x 32 lanes, 8 channels each.
// Online softmax; fp16 gathers (16B/lane), fp32 math. xlr row: [xl(2048) | xr(2048)].
__global__ __launch_bounds__(256) void gat_edge(
    const _Float16* __restrict__ xlr,
    const int* __restrict__ off, const int* __restrict__ csr,
    const float* __restrict__ att, const float* __restrict__ bias,
    float* __restrict__ hout, _Float16* __restrict__ hout16)
{
  __shared__ float red[256 * 8];
  const int n = blockIdx.x;
  const int t = threadIdx.x;
  const int lane32 = t & 31;
  const size_t fo = (size_t)(t >> 5) * CCH + lane32 * 8;

  float xr8[8], att8[8];
  {
    half8_t v = *(const half8_t*)&xlr[(size_t)n * HC2 + HC + fo];
    #pragma unroll
    for (int j = 0; j < 8; j++) xr8[j] = (float)v[j];
    *(float4*)&att8[0] = *(const float4*)&att[fo];
    *(float4*)&att8[4] = *(const float4*)&att[fo + 4];
  }

  float m_run = -INFINITY, d_run = 0.f;
  float acc[8];
  #pragma unroll
  for (int j = 0; j < 8; j++) acc[j] = 0.f;

  const int e0 = off[n], e1 = off[n + 1];
  for (int i = e0; i < e1; i++) {
    const int s = csr[i];
    half8_t v = *(const half8_t*)&xlr[(size_t)s * HC2 + fo];
    float xl8[8];
    float p = 0.f;
    #pragma unroll
    for (int j = 0; j < 8; j++) {
      xl8[j] = (float)v[j];
      float m = xl8[j] + xr8[j];
      m = (m >= 0.f) ? m : 0.2f * m;      // leaky_relu(0.2)
      p = fmaf(att8[j], m, p);
    }
    #pragma unroll
    for (int d = 1; d < 32; d <<= 1) p += __shfl_xor(p, d);
    float m_new = fmaxf(m_run, p);
    float sc = __expf(m_run - m_new);
    float pe = __expf(p - m_new);
    d_run = d_run * sc + pe;
    #pragma unroll
    for (int j = 0; j < 8; j++) acc[j] = fmaf(acc[j], sc, pe * xl8[j]);
    m_run = m_new;
  }

  const float w = 0.125f / (d_run + 1e-16f);
  #pragma unroll
  for (int j = 0; j < 8; j++) red[t * 8 + j] = acc[j] * w;
  __syncthreads();
  if (t < 32) {
    #pragma unroll
    for (int j = 0; j < 8; j++) {
      float s2 = 0.f;
      #pragma unroll
      for (int hh = 0; hh < 8; hh++) s2 += red[(hh * 32 + t) * 8 + j];
      s2 += bias[t * 8 + j];
      hout[(size_t)n * CCH + t * 8 + j] = s2;
      hout16[(size_t)n * CCH + t * 8 + j] = (_Float16)s2;
    }
  }
}

// ---------------------------------------------------------------- pool + head
// grid (NGR, 8): block (g,s) sums slice s of graph g's node range; coalesced.
__global__ __launch_bounds__(256) void pool_kernel2(
    const float* __restrict__ h, const int* __restrict__ goff,
    float* __restrict__ pooled)
{
  const int g = blockIdx.x, s = blockIdx.y, t = threadIdx.x;
  const int n0 = goff[g], n1 = goff[g + 1];
  const int len = n1 - n0;
  const int chunk = (len + 7) / 8;
  const int a = n0 + s * chunk;
  const int b = min(a + chunk, n1);
  float sum = 0.f;
  for (int n = a; n < b; n++) sum += h[(size_t)n * CCH + t];
  if (len > 0) atomicAdd(&pooled[g * CCH + t], sum);
}

__global__ void head_kernel(const float* __restrict__ pooled, const int* __restrict__ goff,
                            const float* __restrict__ hw, const float* __restrict__ hb,
                            float* __restrict__ out)
{
  __shared__ float r[256];
  const int g = blockIdx.x, t = threadIdx.x;
  float c = (float)(goff[g + 1] - goff[g]);
  if (c < 1.f) c = 1.f;
  r[t] = pooled[g * CCH + t] / c * hw[t];
  __syncthreads();
  for (int s2 = 128; s2 > 0; s2 >>= 1) {
    if (t < s2) r[t] += r[t + s2];
    __syncthreads();
  }
  if (t == 0) out[g] = r[0] + hb[0];
}

// ---------------------------------------------------------------- launcher
extern "C" void kernel_launch(void* const* d_in, const int* in_sizes, int n_in,
                              void* d_out, int out_size, void* d_ws, size_t ws_size,
                              hipStream_t stream)
{
  const float* x        = (const float*)d_in[0];
  const int*   ei       = (const int*)d_in[1];
  const int*   batch    = (const int*)d_in[2];
  const float* dense_w  = (const float*)d_in[3];
  const float* dense_b  = (const float*)d_in[4];
  const float* conv_wl  = (const float*)d_in[5];
  const float* conv_wr  = (const float*)d_in[6];
  const float* conv_att = (const float*)d_in[7];
  const float* conv_b   = (const float*)d_in[8];
  const float* head_w   = (const float*)d_in[9];
  const float* head_b   = (const float*)d_in[10];
  float* out = (float*)d_out;

  char* ws = (char*)d_ws;
  size_t off_b = 0;
  auto alloc = [&](size_t bytes) -> char* {
    char* r = ws + off_b;
    off_b += (bytes + 255) & ~(size_t)255;
    return r;
  };
  float*     h      = (float*)alloc((size_t)N_NODES * CCH * 4);          // 10.2 MB
  _Float16*  h16    = (_Float16*)alloc((size_t)M_PAD * CCH * 2);         // 5.2 MB
  _Float16*  x16    = (_Float16*)alloc((size_t)M_PAD * KD_PAD * 2);      // 15.5 MB
  _Float16*  xlr16  = (_Float16*)alloc((size_t)M_PAD * HC2 * 2);         // 82.8 MB
  _Float16*  wdT    = (_Float16*)alloc((size_t)CCH * KD_PAD * 2);        // 0.4 MB
  _Float16*  wcat   = (_Float16*)alloc((size_t)LAYERS * HC2 * CCH * 2);  // 8.4 MB
  int*   offs   = (int*)alloc((N_NODES + 1) * 4);
  int*   cnt    = (int*)alloc(N_NODES * 4);
  int*   csr    = (int*)alloc(E_TOT * 4);
  int*   goff   = (int*)alloc((NGR + 1) * 4);
  float* pooled = (float*)alloc(NGR * CCH * 4);

  // ---- CSR by dst + graph boundaries
  hipMemsetAsync(cnt, 0, N_NODES * 4, stream);
  degree_kernel<<<(E_TOT + 255) / 256, 256, 0, stream>>>(ei, cnt);
  scan_kernel<<<1, 1024, 0, stream>>>(cnt, offs, N_NODES);
  copy_kernel<<<(N_NODES + 255) / 256, 256, 0, stream>>>(offs, cnt, N_NODES);
  fill_kernel<<<(E_TOT + 255) / 256, 256, 0, stream>>>(ei, cnt, csr);
  gbound_kernel<<<(N_NODES + 255) / 256, 256, 0, stream>>>(batch, goff);

  // ---- fp16 conversions / weight transposes (wl|wr concatenated)
  {
    dim3 g(KD_PAD / 256, M_PAD);
    conv_x<<<g, 256, 0, stream>>>(x, x16);
  }
  transpose_w<<<dim3(CCH / 32, KD_PAD / 32), 256, 0, stream>>>(dense_w, wdT, FEAT, CCH, KD_PAD);
  for (int l = 0; l < LAYERS; l++) {
    transpose_w<<<dim3(HC / 32, CCH / 32), 256, 0, stream>>>(
        conv_wl + (size_t)l * CCH * HC, wcat + (size_t)l * HC2 * CCH, CCH, HC, CCH);
    transpose_w<<<dim3(HC / 32, CCH / 32), 256, 0, stream>>>(
        conv_wr + (size_t)l * CCH * HC, wcat + (size_t)l * HC2 * CCH + (size_t)HC * CCH,
        CCH, HC, CCH);
  }

  // ---- dense: h = x @ dense_w + dense_b  (fp32 + fp16 copies)
  gemm_h16<<<dim3(CCH / 128, M_PAD / 128), 256, 0, stream>>>(
      x16, wdT, h, h16, dense_b, N_NODES, CCH, KD_PAD);

  // ---- 4 GATv2 layers (one fused xl|xr GEMM per layer)
  for (int l = 0; l < LAYERS; l++) {
    gemm_h16<<<dim3(HC2 / 128, M_PAD / 128), 256, 0, stream>>>(
        h16, wcat + (size_t)l * HC2 * CCH, nullptr, xlr16, nullptr, N_NODES, HC2, CCH);
    gat_edge<<<N_NODES, 256, 0, stream>>>(xlr16, offs, csr,
                                          conv_att + (size_t)l * HC,
                                          conv_b + (size_t)l * CCH, h, h16);
  }

  // ---- global mean pool + head
  hipMemsetAsync(pooled, 0, NGR * CCH * 4, stream);
  pool_kernel2<<<dim3(NGR, 8), 256, 0, stream>>>(h, goff, pooled);
  head_kernel<<<NGR, 256, 0, stream>>>(pooled, goff, head_w, head_b, out);
}

// Round 4
// 808.275 us; speedup vs baseline: 2.9201x; 1.0123x over previous
//
#include <hip/hip_runtime.h>
#include <hip/hip_bf16.h>
#include <math.h>

#define N_NODES 10000
#define M_PAD   10112          // 79 * 128
#define N_EDGES 160000
#define FEAT 739
#define KD_PAD 768             // FEAT padded to 32
#define CCH 256
#define HEADS 8
#define LAYERS 4
#define NGR 16
#define HC 2048                // HEADS * CCH
#define HC2 4096               // xl|xr concatenated row
#define E_TOT (N_EDGES + N_NODES)

typedef _Float16 half8_t __attribute__((ext_vector_type(8)));
typedef float    f32x4   __attribute__((ext_vector_type(4)));

__device__ __forceinline__ void gload16(const void* g, void* l) {
  __builtin_amdgcn_global_load_lds(
      (const __attribute__((address_space(1))) void*)g,
      (__attribute__((address_space(3))) void*)l, 16, 0, 0);
}

// ---------------------------------------------------------------- MFMA GEMM (fp16 in, fp32 acc)
__global__ __launch_bounds__(256) void gemm_h16(
    const _Float16* __restrict__ A,   // [M_PAD][K]
    const _Float16* __restrict__ BT,  // [N][K]
    float* __restrict__ C,            // [M][N] or null
    _Float16* __restrict__ C16,       // [M][N] or null
    const float* __restrict__ bias,   // [N] or null
    int M, int N, int K)
{
  __shared__ __align__(16) _Float16 As[2][128][32];
  __shared__ __align__(16) _Float16 Bs[2][128][32];
  const int tid  = threadIdx.x;
  const int wave = tid >> 6, lane = tid & 63;
  const int wm = wave >> 1, wn = wave & 1;
  const int m0 = blockIdx.y * 128, n0 = blockIdx.x * 128;
  const int l15 = lane & 15, l4 = lane >> 4;

  f32x4 acc[4][4];
  #pragma unroll
  for (int i = 0; i < 4; i++)
    #pragma unroll
    for (int j = 0; j < 4; j++) acc[i][j] = (f32x4){0.f, 0.f, 0.f, 0.f};

  auto stage = [&](int buf, int k0) {
    #pragma unroll
    for (int i = 0; i < 2; i++) {
      int q = i * 256 + tid;
      int row = q >> 2, ch = (q & 3) * 8;
      gload16(&A[(size_t)(m0 + row) * K + k0 + ch], &As[buf][row][ch]);
    }
    #pragma unroll
    for (int i = 0; i < 2; i++) {
      int q = i * 256 + tid;
      int row = q >> 2, ch = (q & 3) * 8;
      gload16(&BT[(size_t)(n0 + row) * K + k0 + ch], &Bs[buf][row][ch]);
    }
  };

  const int NT = K >> 5;
  stage(0, 0);
  for (int t = 0; t < NT; t++) {
    __syncthreads();
    if (t + 1 < NT) stage((t + 1) & 1, (t + 1) << 5);
    const int b = t & 1;
    half8_t af[4], bf[4];
    #pragma unroll
    for (int f = 0; f < 4; f++)
      af[f] = *(const half8_t*)&As[b][wm * 64 + f * 16 + l15][l4 * 8];
    #pragma unroll
    for (int f = 0; f < 4; f++)
      bf[f] = *(const half8_t*)&Bs[b][wn * 64 + f * 16 + l15][l4 * 8];
    #pragma unroll
    for (int i = 0; i < 4; i++)
      #pragma unroll
      for (int j = 0; j < 4; j++)
        acc[i][j] = __builtin_amdgcn_mfma_f32_16x16x32_f16(af[i], bf[j], acc[i][j], 0, 0, 0);
  }

  #pragma unroll
  for (int j = 0; j < 4; j++) {
    const int col = n0 + wn * 64 + j * 16 + l15;
    const float bv = bias ? bias[col] : 0.f;
    #pragma unroll
    for (int i = 0; i < 4; i++) {
      #pragma unroll
      for (int r = 0; r < 4; r++) {
        const int row = m0 + wm * 64 + i * 16 + l4 * 4 + r;
        if (row < M) {
          const float v = acc[i][j][r] + bv;
          if (C)   C[(size_t)row * N + col]   = v;
          if (C16) C16[(size_t)row * N + col] = (_Float16)v;
        }
      }
    }
  }
}

// ---------------------------------------------------------------- converts / transposes
__global__ __launch_bounds__(256) void transpose_w(
    const float* __restrict__ in, _Float16* __restrict__ out, int K, int N, int Kpad)
{
  __shared__ float tile[32][33];
  const int kb = blockIdx.y * 32, nb = blockIdx.x * 32;
  const int tx = threadIdx.x & 31, ty = threadIdx.x >> 5;
  #pragma unroll
  for (int i = 0; i < 32; i += 8) {
    int k = kb + ty + i;
    tile[ty + i][tx] = (k < K) ? in[(size_t)k * N + nb + tx] : 0.f;
  }
  __syncthreads();
  #pragma unroll
  for (int i = 0; i < 32; i += 8) {
    int n = nb + ty + i;
    out[(size_t)n * Kpad + kb + tx] = (_Float16)tile[tx][ty + i];
  }
}

__global__ void conv_x(const float* __restrict__ x, _Float16* __restrict__ x16)
{
  const int r = blockIdx.y;
  const int c = blockIdx.x * 256 + threadIdx.x;
  float v = (r < N_NODES && c < FEAT) ? x[(size_t)r * FEAT + c] : 0.f;
  x16[(size_t)r * KD_PAD + c] = (_Float16)v;
}

// ---------------------------------------------------------------- CSR build
__global__ void degree_kernel(const int* __restrict__ ei, int* __restrict__ cnt)
{
  int e = blockIdx.x * 256 + threadIdx.x;
  if (e >= E_TOT) return;
  int d = (e < N_EDGES) ? ei[N_EDGES + e] : (e - N_EDGES);
  atomicAdd(&cnt[d], 1);
}

__global__ void scan_kernel(const int* __restrict__ cnt, int* __restrict__ off, int n)
{
  __shared__ int part[1024];
  const int t = threadIdx.x;
  const int chunk = (n + 1023) / 1024;
  int s = 0;
  for (int i = 0; i < chunk; i++) {
    int idx = t * chunk + i;
    if (idx < n) s += cnt[idx];
  }
  part[t] = s;
  __syncthreads();
  for (int d = 1; d < 1024; d <<= 1) {
    int v = (t >= d) ? part[t - d] : 0;
    __syncthreads();
    part[t] += v;
    __syncthreads();
  }
  int run = (t == 0) ? 0 : part[t - 1];
  for (int i = 0; i < chunk; i++) {
    int idx = t * chunk + i;
    if (idx < n) { off[idx] = run; run += cnt[idx]; }
  }
  if (t == 1023) off[n] = part[1023];
}

__global__ void copy_kernel(const int* __restrict__ src, int* __restrict__ dst, int n)
{
  int i = blockIdx.x * 256 + threadIdx.x;
  if (i < n) dst[i] = src[i];
}

__global__ void fill_kernel(const int* __restrict__ ei, int* __restrict__ cursor,
                            int* __restrict__ csr)
{
  int e = blockIdx.x * 256 + threadIdx.x;
  if (e >= E_TOT) return;
  int s, d;
  if (e < N_EDGES) { s = ei[e]; d = ei[N_EDGES + e]; }
  else             { s = e - N_EDGES; d = s; }
  int pos = atomicAdd(&cursor[d], 1);
  csr[pos] = s;
}

__global__ void gbound_kernel(const int* __restrict__ batch, int* __restrict__ goff)
{
  int n = blockIdx.x * 256 + threadIdx.x;
  if (n >= N_NODES) return;
  if (n == 0) {
    for (int g = 0; g <= batch[0]; g++) goff[g] = 0;
  } else {
    int b0 = batch[n - 1], b1 = batch[n];
    for (int g = b0 + 1; g <= b1; g++) goff[g] = n;
  }
  if (n == N_NODES - 1) {
    for (int g = batch[n] + 1; g <= NGR; g++) goff[g] = N_NODES;
  }
}

// ---------------------------------------------------------------- fused GATv2 edge pass
// 1 block = 1 dst node; 8 heads x 32 lanes, 8 ch/lane. Online softmax with
// 2-edge ILP, deferred rescale, pair-ahead prefetch, packed-fp16 score math.
__global__ __launch_bounds__(256) void gat_edge(
    const _Float16* __restrict__ xlr,
    const int* __restrict__ off, const int* __restrict__ csr,
    const float* __restrict__ att, const float* __restrict__ bias,
    float* __restrict__ hout, _Float16* __restrict__ hout16)
{
  __shared__ float red2[8][256];
  const int n = blockIdx.x;
  const int t = threadIdx.x;
  const size_t fo = (size_t)(t >> 5) * CCH + (t & 31) * 8;

  half8_t vxr = *(const half8_t*)&xlr[(size_t)n * HC2 + HC + fo];
  float att8[8];
  *(float4*)&att8[0] = *(const float4*)&att[fo];
  *(float4*)&att8[4] = *(const float4*)&att[fo + 4];

  float m_run = -INFINITY, d_run = 0.f;
  float acc[8];
  #pragma unroll
  for (int j = 0; j < 8; j++) acc[j] = 0.f;

  const int e0 = off[n], e1 = off[n + 1];
  const int cnt2 = e1 - e0;
  const int npair = cnt2 >> 1;
  const int tail  = cnt2 & 1;

  // score of one gathered row (packed fp16 add/leaky, fp32 mix-fma dot)
  auto score = [&](half8_t vx) -> float {
    half8_t m  = vx + vxr;
    half8_t lm = __builtin_elementwise_max(m, m * (_Float16)0.2f);
    float p = 0.f;
    #pragma unroll
    for (int j = 0; j < 8; j++) p = fmaf((float)lm[j], att8[j], p);
    return p;
  };

  int i = e0;
  half8_t va, vb;
  if (npair > 0) {
    va = *(const half8_t*)&xlr[(size_t)csr[i] * HC2 + fo];
    vb = *(const half8_t*)&xlr[(size_t)csr[i + 1] * HC2 + fo];
  } else if (tail) {
    va = *(const half8_t*)&xlr[(size_t)csr[i] * HC2 + fo];
  }

  for (int p2 = 0; p2 < npair; p2++) {
    half8_t na, nb;
    const bool morePair = (p2 + 1 < npair);
    const bool moreOne  = (!morePair) && tail;
    if (morePair) {
      na = *(const half8_t*)&xlr[(size_t)csr[i + 2] * HC2 + fo];
      nb = *(const half8_t*)&xlr[(size_t)csr[i + 3] * HC2 + fo];
    } else if (moreOne) {
      na = *(const half8_t*)&xlr[(size_t)csr[i + 2] * HC2 + fo];
    }

    float p0 = score(va);
    float p1 = score(vb);
    #pragma unroll
    for (int d = 1; d < 32; d <<= 1) {
      p0 += __shfl_xor(p0, d);
      p1 += __shfl_xor(p1, d);
    }
    float m_new = fmaxf(fmaxf(m_run, p0), p1);   // v_max3
    if (m_new > m_run) {                          // deferred rescale
      float sc = __expf(m_run - m_new);           // exp(-inf)=0 first time
      d_run *= sc;
      #pragma unroll
      for (int j = 0; j < 8; j++) acc[j] *= sc;
      m_run = m_new;
    }
    float pe0 = __expf(p0 - m_run);
    float pe1 = __expf(p1 - m_run);
    d_run += pe0 + pe1;
    #pragma unroll
    for (int j = 0; j < 8; j++) {
      float a = fmaf((float)va[j], pe0, acc[j]);
      acc[j] = fmaf((float)vb[j], pe1, a);
    }
    va = na; vb = nb; i += 2;
  }

  if (tail) {
    float p0 = score(va);
    #pragma unroll
    for (int d = 1; d < 32; d <<= 1) p0 += __shfl_xor(p0, d);
    float m_new = fmaxf(m_run, p0);
    if (m_new > m_run) {
      float sc = __expf(m_run - m_new);
      d_run *= sc;
      #pragma unroll
      for (int j = 0; j < 8; j++) acc[j] *= sc;
      m_run = m_new;
    }
    float pe0 = __expf(p0 - m_run);
    d_run += pe0;
    #pragma unroll
    for (int j = 0; j < 8; j++) acc[j] = fmaf((float)va[j], pe0, acc[j]);
  }

  const float w = 0.125f / (d_run + 1e-16f);
  #pragma unroll
  for (int j = 0; j < 8; j++) red2[j][t] = acc[j] * w;  // conflict-free layout
  __syncthreads();
  if (t < 32) {
    #pragma unroll
    for (int j = 0; j < 8; j++) {
      float s2 = 0.f;
      #pragma unroll
      for (int hh = 0; hh < 8; hh++) s2 += red2[j][hh * 32 + t];
      s2 += bias[t * 8 + j];
      hout[(size_t)n * CCH + t * 8 + j] = s2;
      hout16[(size_t)n * CCH + t * 8 + j] = (_Float16)s2;
    }
  }
}

// ---------------------------------------------------------------- pool + head
__global__ __launch_bounds__(256) void pool_kernel2(
    const float* __restrict__ h, const int* __restrict__ goff,
    float* __restrict__ pooled)
{
  const int g = blockIdx.x, s = blockIdx.y, t = threadIdx.x;
  const int n0 = goff[g], n1 = goff[g + 1];
  const int len = n1 - n0;
  const int chunk = (len + 7) / 8;
  const int a = n0 + s * chunk;
  const int b = min(a + chunk, n1);
  float sum = 0.f;
  for (int n = a; n < b; n++) sum += h[(size_t)n * CCH + t];
  if (len > 0) atomicAdd(&pooled[g * CCH + t], sum);
}

__global__ void head_kernel(const float* __restrict__ pooled, const int* __restrict__ goff,
                            const float* __restrict__ hw, const float* __restrict__ hb,
                            float* __restrict__ out)
{
  __shared__ float r[256];
  const int g = blockIdx.x, t = threadIdx.x;
  float c = (float)(goff[g + 1] - goff[g]);
  if (c < 1.f) c = 1.f;
  r[t] = pooled[g * CCH + t] / c * hw[t];
  __syncthreads();
  for (int s2 = 128; s2 > 0; s2 >>= 1) {
    if (t < s2) r[t] += r[t + s2];
    __syncthreads();
  }
  if (t == 0) out[g] = r[0] + hb[0];
}

// ---------------------------------------------------------------- launcher
extern "C" void kernel_launch(void* const* d_in, const int* in_sizes, int n_in,
                              void* d_out, int out_size, void* d_ws, size_t ws_size,
                              hipStream_t stream)
{
  const float* x        = (const float*)d_in[0];
  const int*   ei       = (const int*)d_in[1];
  const int*   batch    = (const int*)d_in[2];
  const float* dense_w  = (const float*)d_in[3];
  const float* dense_b  = (const float*)d_in[4];
  const float* conv_wl  = (const float*)d_in[5];
  const float* conv_wr  = (const float*)d_in[6];
  const float* conv_att = (const float*)d_in[7];
  const float* conv_b   = (const float*)d_in[8];
  const float* head_w   = (const float*)d_in[9];
  const float* head_b   = (const float*)d_in[10];
  float* out = (float*)d_out;

  char* ws = (char*)d_ws;
  size_t off_b = 0;
  auto alloc = [&](size_t bytes) -> char* {
    char* r = ws + off_b;
    off_b += (bytes + 255) & ~(size_t)255;
    return r;
  };
  float*     h      = (float*)alloc((size_t)N_NODES * CCH * 4);
  _Float16*  h16    = (_Float16*)alloc((size_t)M_PAD * CCH * 2);
  _Float16*  x16    = (_Float16*)alloc((size_t)M_PAD * KD_PAD * 2);
  _Float16*  xlr16  = (_Float16*)alloc((size_t)M_PAD * HC2 * 2);
  _Float16*  wdT    = (_Float16*)alloc((size_t)CCH * KD_PAD * 2);
  _Float16*  wcat   = (_Float16*)alloc((size_t)LAYERS * HC2 * CCH * 2);
  int*   offs   = (int*)alloc((N_NODES + 1) * 4);
  int*   cnt    = (int*)alloc(N_NODES * 4);
  int*   csr    = (int*)alloc(E_TOT * 4);
  int*   goff   = (int*)alloc((NGR + 1) * 4);
  float* pooled = (float*)alloc(NGR * CCH * 4);

  // ---- CSR by dst + graph boundaries
  hipMemsetAsync(cnt, 0, N_NODES * 4, stream);
  degree_kernel<<<(E_TOT + 255) / 256, 256, 0, stream>>>(ei, cnt);
  scan_kernel<<<1, 1024, 0, stream>>>(cnt, offs, N_NODES);
  copy_kernel<<<(N_NODES + 255) / 256, 256, 0, stream>>>(offs, cnt, N_NODES);
  fill_kernel<<<(E_TOT + 255) / 256, 256, 0, stream>>>(ei, cnt, csr);
  gbound_kernel<<<(N_NODES + 255) / 256, 256, 0, stream>>>(batch, goff);

  // ---- fp16 conversions / weight transposes (wl|wr concatenated)
  {
    dim3 g(KD_PAD / 256, M_PAD);
    conv_x<<<g, 256, 0, stream>>>(x, x16);
  }
  transpose_w<<<dim3(CCH / 32, KD_PAD / 32), 256, 0, stream>>>(dense_w, wdT, FEAT, CCH, KD_PAD);
  for (int l = 0; l < LAYERS; l++) {
    transpose_w<<<dim3(HC / 32, CCH / 32), 256, 0, stream>>>(
        conv_wl + (size_t)l * CCH * HC, wcat + (size_t)l * HC2 * CCH, CCH, HC, CCH);
    transpose_w<<<dim3(HC / 32, CCH / 32), 256, 0, stream>>>(
        conv_wr + (size_t)l * CCH * HC, wcat + (size_t)l * HC2 * CCH + (size_t)HC * CCH,
        CCH, HC, CCH);
  }

  // ---- dense: h = x @ dense_w + dense_b
  gemm_h16<<<dim3(CCH / 128, M_PAD / 128), 256, 0, stream>>>(
      x16, wdT, h, h16, dense_b, N_NODES, CCH, KD_PAD);

  // ---- 4 GATv2 layers
  for (int l = 0; l < LAYERS; l++) {
    gemm_h16<<<dim3(HC2 / 128, M_PAD / 128), 256, 0, stream>>>(
        h16, wcat + (size_t)l * HC2 * CCH, nullptr, xlr16, nullptr, N_NODES, HC2, CCH);
    gat_edge<<<N_NODES, 256, 0, stream>>>(xlr16, offs, csr,
                                          conv_att + (size_t)l * HC,
                                          conv_b + (size_t)l * CCH, h, h16);
  }

  // ---- global mean pool + head
  hipMemsetAsync(pooled, 0, NGR * CCH * 4, stream);
  pool_kernel2<<<dim3(NGR, 8), 256, 0, stream>>>(h, goff, pooled);
  head_kernel<<<NGR, 256, 0, stream>>>(pooled, goff, head_w, head_b, out);
}